// Round 5
// baseline (660.432 us; speedup 1.0000x reference)
//
#include <hip/hip_runtime.h>

#define N_NODES 100000
#define N_EDGES 3200000
#define D_FEAT  512
#define HIDDEN  16
#define NCLS    6
#define BSH     7                      // bucket = col >> 7
#define BNODES  128                    // nodes per bucket
#define NBUK    782                    // ceil(N_NODES/128)
#define TILE    8192
#define NBLK_A  391                    // ceil(N_EDGES/TILE)

// ---------- helpers ----------

// edge_index may arrive as int32 (JAX x64 disabled) or int64 (x64 enabled).
// flag==1 means int64 layout (pairs of i32, low word first, little-endian).
__device__ __forceinline__ int eidx(const int* __restrict__ ei, int is64, int pos) {
    return is64 ? ei[2 * (long long)pos] : ei[pos];
}

__global__ void k_detect(const int* __restrict__ ei, int* __restrict__ flag) {
    int v = ei[2 * threadIdx.x + 1];
    unsigned long long b = __ballot(v != 0);
    if (threadIdx.x == 0) flag[0] = (b == 0ULL) ? 1 : 0;
}

// ---------- bucket CSR build ----------

__global__ __launch_bounds__(256)
void k_bhist(const int* __restrict__ ei, const int* __restrict__ flag,
             int* __restrict__ bcnt) {
    __shared__ int lh[NBUK];
    for (int i = threadIdx.x; i < NBUK; i += 256) lh[i] = 0;
    __syncthreads();
    int is64 = flag[0];
    int s = blockIdx.x * TILE, e1 = min(s + TILE, N_EDGES);
    for (int e = s + threadIdx.x; e < e1; e += 256) {
        int c = eidx(ei, is64, N_EDGES + e);
        atomicAdd(&lh[c >> BSH], 1);
    }
    __syncthreads();
    for (int i = threadIdx.x; i < NBUK; i += 256)
        if (lh[i]) atomicAdd(&bcnt[i], lh[i]);
}

// scan of NBUK bucket counts -> bstart (excl, +total at [NBUK]) and bcursor
__global__ void k_bscan(const int* __restrict__ bcnt, int* __restrict__ bstart,
                        int* __restrict__ bcursor) {
    __shared__ int s[1024];
    int t = threadIdx.x;
    int v = (t < NBUK) ? bcnt[t] : 0;
    s[t] = v;
    __syncthreads();
    for (int off = 1; off < 1024; off <<= 1) {
        int u = (t >= off) ? s[t - off] : 0;
        __syncthreads();
        s[t] += u;
        __syncthreads();
    }
    int excl = s[t] - v;
    if (t <= NBUK) bstart[t] = excl;
    if (t < NBUK)  bcursor[t] = excl;
}

// scatter edges into bucket-major abuf with block-reserved runs
// pack: x = row | (col&127)<<17   (row < 2^17), y = bits(w)
__global__ __launch_bounds__(256)
void k_bscat(const int* __restrict__ ei, const float* __restrict__ ew,
             const int* __restrict__ flag, int* __restrict__ bcursor,
             uint2* __restrict__ abuf) {
    __shared__ int lh[NBUK];
    __shared__ int lbase[NBUK];
    __shared__ int lcur[NBUK];
    for (int i = threadIdx.x; i < NBUK; i += 256) { lh[i] = 0; lcur[i] = 0; }
    __syncthreads();
    int is64 = flag[0];
    int s = blockIdx.x * TILE, e1 = min(s + TILE, N_EDGES);
    for (int e = s + threadIdx.x; e < e1; e += 256) {
        int c = eidx(ei, is64, N_EDGES + e);
        atomicAdd(&lh[c >> BSH], 1);
    }
    __syncthreads();
    for (int i = threadIdx.x; i < NBUK; i += 256)
        if (lh[i]) lbase[i] = atomicAdd(&bcursor[i], lh[i]);
    __syncthreads();
    for (int e = s + threadIdx.x; e < e1; e += 256) {
        int r = eidx(ei, is64, e);
        int c = eidx(ei, is64, N_EDGES + e);
        float w = ew[e];
        int b = c >> BSH;
        int off = atomicAdd(&lcur[b], 1);
        abuf[lbase[b] + off] = make_uint2((unsigned)r | ((unsigned)(c & (BNODES - 1)) << 17),
                                          __float_as_uint(w));
    }
}

// per-bucket degree -> dinv  (deg = 1 self-loop + sum w)
__global__ __launch_bounds__(256)
void k_degB(const int* __restrict__ bstart, const uint2* __restrict__ abuf,
            float* __restrict__ dinv) {
    __shared__ float wsum[BNODES];
    int t = threadIdx.x, b = blockIdx.x;
    if (t < BNODES) wsum[t] = 0.0f;
    __syncthreads();
    int s0 = bstart[b], s1 = bstart[b + 1];
    for (int k = s0 + t; k < s1; k += 256) {
        uint2 a = abuf[k];
        atomicAdd(&wsum[a.x >> 17], __uint_as_float(a.y));
    }
    __syncthreads();
    int node = b * BNODES + t;
    if (t < BNODES && node < N_NODES) dinv[node] = rsqrtf(1.0f + wsum[t]);
}

// ---------- layer 1 transform: h1 = x @ W1 ----------
// Thread-per-row, 16 k-chunks of 32, x tile transposed in LDS (pad 257).
// W1 uniform -> s_load; register double-buffer hides HBM latency.

__global__ __launch_bounds__(256)
void k_gemm1(const float* __restrict__ x, const float* __restrict__ W1g,
             float* __restrict__ h1) {
    __shared__ float xT[32 * 257];
    const int t = threadIdx.x;
    const int row0 = blockIdx.x * 256;
    const int myrow = row0 + t;

    float4 rg[8], rn[8];
#pragma unroll
    for (int p = 0; p < 8; ++p) {
        int f = t + 256 * p;
        int lr = f >> 3, lc = f & 7;
        int gr = min(row0 + lr, N_NODES - 1);
        rg[p] = *(const float4*)(x + (size_t)gr * D_FEAT + 4 * lc);
    }

    float acc[16];
#pragma unroll
    for (int j = 0; j < 16; ++j) acc[j] = 0.0f;

    for (int ch = 0; ch < 16; ++ch) {
        __syncthreads();
#pragma unroll
        for (int p = 0; p < 8; ++p) {
            int f = t + 256 * p;
            int lr = f >> 3, lc = f & 7;
            xT[(4 * lc + 0) * 257 + lr] = rg[p].x;
            xT[(4 * lc + 1) * 257 + lr] = rg[p].y;
            xT[(4 * lc + 2) * 257 + lr] = rg[p].z;
            xT[(4 * lc + 3) * 257 + lr] = rg[p].w;
        }
        if (ch < 15) {
            int k0n = (ch + 1) * 32;
#pragma unroll
            for (int p = 0; p < 8; ++p) {
                int f = t + 256 * p;
                int lr = f >> 3, lc = f & 7;
                int gr = min(row0 + lr, N_NODES - 1);
                rn[p] = *(const float4*)(x + (size_t)gr * D_FEAT + k0n + 4 * lc);
            }
        }
        __syncthreads();
        const int k0 = ch * 32;
#pragma unroll
        for (int k = 0; k < 32; ++k) {
            float xk = xT[k * 257 + t];
            const float* wr = W1g + ((size_t)(k0 + k) << 4);
#pragma unroll
            for (int j = 0; j < 16; ++j) acc[j] = fmaf(xk, wr[j], acc[j]);
        }
#pragma unroll
        for (int p = 0; p < 8; ++p) rg[p] = rn[p];
    }

    if (myrow < N_NODES) {
        float4* o = (float4*)(h1 + (size_t)myrow * HIDDEN);
        o[0] = make_float4(acc[0],  acc[1],  acc[2],  acc[3]);
        o[1] = make_float4(acc[4],  acc[5],  acc[6],  acc[7]);
        o[2] = make_float4(acc[8],  acc[9],  acc[10], acc[11]);
        o[3] = make_float4(acc[12], acc[13], acc[14], acc[15]);
    }
}

// ---------- layer 1 aggregate (LDS tile) + bias + self-loop + gemm2 ----------
// 4 lanes per edge, each owns 4 features (float4 of h1 row). acc padded to 17.

__global__ __launch_bounds__(256)
void k_agg1(const int* __restrict__ bstart, const uint2* __restrict__ abuf,
            const float* __restrict__ dinv, const float* __restrict__ h1,
            const float* __restrict__ b1, const float* __restrict__ W2g,
            float* __restrict__ x1, float* __restrict__ h2p) {
    __shared__ float acc[BNODES][17];
    __shared__ float sW2[HIDDEN * NCLS];
    int t = threadIdx.x, b = blockIdx.x;
    if (t < HIDDEN * NCLS) sW2[t] = W2g[t];
    for (int i = t; i < BNODES * 17; i += 256) ((float*)acc)[i] = 0.0f;
    __syncthreads();

    int s0 = bstart[b], s1 = bstart[b + 1];
    int q = t & 3;
    for (int k0 = s0; k0 < s1; k0 += 64) {
        int k = k0 + (t >> 2);
        if (k < s1) {
            uint2 a = abuf[k];
            int r  = (int)(a.x & 0x1FFFFu);
            int ln = (int)(a.x >> 17);
            float wn = __uint_as_float(a.y) * dinv[r];
            float4 h = *(const float4*)(h1 + (size_t)r * HIDDEN + 4 * q);
            atomicAdd(&acc[ln][4 * q + 0], wn * h.x);
            atomicAdd(&acc[ln][4 * q + 1], wn * h.y);
            atomicAdd(&acc[ln][4 * q + 2], wn * h.z);
            atomicAdd(&acc[ln][4 * q + 3], wn * h.w);
        }
    }
    __syncthreads();

    // finalize: 2 threads/node, 8 features each
    int ln = t >> 1, qq = t & 1;
    int node = b * BNODES + ln;
    if (node < N_NODES) {
        float di = dinv[node], d2 = di * di;
        const float* h1r = h1 + (size_t)node * HIDDEN + 8 * qq;
        float v[8];
#pragma unroll
        for (int jj = 0; jj < 8; ++jj) {
            int j = 8 * qq + jj;
            v[jj] = di * acc[ln][j] + d2 * h1r[jj] + b1[j];
            acc[ln][j] = v[jj];                     // reuse tile for gemm2
        }
        float4* xo = (float4*)(x1 + (size_t)node * HIDDEN + 8 * qq);
        xo[0] = make_float4(v[0], v[1], v[2], v[3]);
        xo[1] = make_float4(v[4], v[5], v[6], v[7]);
    }
    __syncthreads();
    if (node < N_NODES) {
#pragma unroll
        for (int cc = 0; cc < 3; ++cc) {
            int c = 3 * qq + cc;
            float a = 0.0f;
#pragma unroll
            for (int kk = 0; kk < HIDDEN; ++kk)
                a = fmaf(acc[ln][kk], sW2[kk * NCLS + c], a);
            h2p[(size_t)node * 8 + c] = a;
        }
        h2p[(size_t)node * 8 + 6 + qq] = 0.0f;      // pad slots
    }
}

// ---------- layer 2 aggregate (LDS tile) + self-loop + log_softmax ----------
// 2 lanes per edge on padded h2p[N,8]; acc padded to 9.

__global__ __launch_bounds__(256)
void k_agg2(const int* __restrict__ bstart, const uint2* __restrict__ abuf,
            const float* __restrict__ dinv, const float* __restrict__ h2p,
            const float* __restrict__ b2, float* __restrict__ out) {
    __shared__ float acc[BNODES][9];
    int t = threadIdx.x, b = blockIdx.x;
    for (int i = t; i < BNODES * 9; i += 256) ((float*)acc)[i] = 0.0f;
    __syncthreads();

    int s0 = bstart[b], s1 = bstart[b + 1];
    int q = t & 1;
    for (int k0 = s0; k0 < s1; k0 += 128) {
        int k = k0 + (t >> 1);
        if (k < s1) {
            uint2 a = abuf[k];
            int r  = (int)(a.x & 0x1FFFFu);
            int ln = (int)(a.x >> 17);
            float wn = __uint_as_float(a.y) * dinv[r];
            float4 h = *(const float4*)(h2p + (size_t)r * 8 + 4 * q);
            if (q == 0) {
                atomicAdd(&acc[ln][0], wn * h.x);
                atomicAdd(&acc[ln][1], wn * h.y);
                atomicAdd(&acc[ln][2], wn * h.z);
                atomicAdd(&acc[ln][3], wn * h.w);
            } else {
                atomicAdd(&acc[ln][4], wn * h.x);
                atomicAdd(&acc[ln][5], wn * h.y);
            }
        }
    }
    __syncthreads();

    int node = b * BNODES + t;
    if (t < BNODES && node < N_NODES) {
        float di = dinv[node], d2 = di * di;
        const float* hr = h2p + (size_t)node * 8;
        float v[NCLS];
        float m = -1e30f;
#pragma unroll
        for (int c = 0; c < NCLS; ++c) {
            v[c] = di * acc[t][c] + d2 * hr[c] + b2[c];
            m = fmaxf(m, v[c]);
        }
        float ssum = 0.0f;
#pragma unroll
        for (int c = 0; c < NCLS; ++c) ssum += __expf(v[c] - m);
        float l = __logf(ssum);
#pragma unroll
        for (int c = 0; c < NCLS; ++c) out[(size_t)node * NCLS + c] = v[c] - m - l;
    }
}

// ---------- tier-3 atomic fallback kernels (small ws) ----------

__global__ void k_initdeg(float* __restrict__ deg) {
    int i = blockIdx.x * 256 + threadIdx.x;
    if (i < N_NODES) deg[i] = 1.0f;
}

__global__ void k_degacc(const int* __restrict__ ei, const float* __restrict__ w,
                         const int* __restrict__ flag, float* __restrict__ deg) {
    int e = blockIdx.x * 256 + threadIdx.x;
    if (e >= N_EDGES) return;
    int c = eidx(ei, flag[0], N_EDGES + e);
    atomicAdd(&deg[c], w[e]);
}

__global__ void k_dinv(float* __restrict__ deg) {
    int i = blockIdx.x * 256 + threadIdx.x;
    if (i < N_NODES) {
        float d = deg[i];
        deg[i] = (d > 0.0f) ? rsqrtf(d) : 0.0f;
    }
}

__global__ __launch_bounds__(256)
void k_scatter1(const int* __restrict__ ei, const float* __restrict__ w,
                const int* __restrict__ flag, const float* __restrict__ dinv,
                const float* __restrict__ h1, float* __restrict__ agg1) {
    int t = blockIdx.x * 256 + threadIdx.x;
    if (t >= N_EDGES * HIDDEN) return;
    int e = t >> 4, j = t & 15;
    int is64 = flag[0];
    int r = eidx(ei, is64, e);
    int c = eidx(ei, is64, N_EDGES + e);
    float nrm = dinv[r] * w[e] * dinv[c];
    atomicAdd(&agg1[(size_t)c * HIDDEN + j], nrm * h1[(size_t)r * HIDDEN + j]);
}

__global__ void k_fin1_gemm2(const float* __restrict__ b1, const float* __restrict__ W2,
                             const float* __restrict__ dinv, const float* __restrict__ h1,
                             float* __restrict__ x1, float* __restrict__ h2) {
    int i = blockIdx.x * 256 + threadIdx.x;
    if (i >= N_NODES) return;
    float d2 = dinv[i] * dinv[i];
    float v[HIDDEN];
#pragma unroll
    for (int k = 0; k < HIDDEN; ++k)
        v[k] = x1[(size_t)i * HIDDEN + k] + d2 * h1[(size_t)i * HIDDEN + k] + b1[k];
#pragma unroll
    for (int k = 0; k < HIDDEN; ++k)
        x1[(size_t)i * HIDDEN + k] = v[k];
#pragma unroll
    for (int j = 0; j < NCLS; ++j) {
        float a = 0.0f;
#pragma unroll
        for (int k = 0; k < HIDDEN; ++k) a = fmaf(v[k], W2[k * NCLS + j], a);
        h2[(size_t)i * NCLS + j] = a;
    }
}

__global__ __launch_bounds__(256)
void k_scatter2(const int* __restrict__ ei, const float* __restrict__ w,
                const int* __restrict__ flag, const float* __restrict__ dinv,
                const float* __restrict__ h2, float* __restrict__ agg2) {
    int t = blockIdx.x * 256 + threadIdx.x;
    if (t >= N_EDGES * NCLS) return;
    int e = t / NCLS, j = t - e * NCLS;
    int is64 = flag[0];
    int r = eidx(ei, is64, e);
    int c = eidx(ei, is64, N_EDGES + e);
    float nrm = dinv[r] * w[e] * dinv[c];
    atomicAdd(&agg2[(size_t)c * NCLS + j], nrm * h2[(size_t)r * NCLS + j]);
}

__global__ void k_final(const float* __restrict__ agg2, const float* __restrict__ h2,
                        const float* __restrict__ dinv, const float* __restrict__ b2,
                        float* __restrict__ out) {
    int i = blockIdx.x * 256 + threadIdx.x;
    if (i >= N_NODES) return;
    float d2 = dinv[i] * dinv[i];
    float v[NCLS];
    float m = -1e30f;
#pragma unroll
    for (int j = 0; j < NCLS; ++j) {
        v[j] = agg2[(size_t)i * NCLS + j] + d2 * h2[(size_t)i * NCLS + j] + b2[j];
        m = fmaxf(m, v[j]);
    }
    float s = 0.0f;
#pragma unroll
    for (int j = 0; j < NCLS; ++j) s += __expf(v[j] - m);
    float l = __logf(s);
#pragma unroll
    for (int j = 0; j < NCLS; ++j) out[(size_t)i * NCLS + j] = v[j] - m - l;
}

// ---------- launch ----------

extern "C" void kernel_launch(void* const* d_in, const int* in_sizes, int n_in,
                              void* d_out, int out_size, void* d_ws, size_t ws_size,
                              hipStream_t stream) {
    const float* x  = (const float*)d_in[0];
    const float* W1 = (const float*)d_in[1];
    const float* b1 = (const float*)d_in[2];
    const float* W2 = (const float*)d_in[3];
    const float* b2 = (const float*)d_in[4];
    const float* ew = (const float*)d_in[5];
    const int*   ei = (const int*)d_in[6];

    float* out = (float*)d_out;
    float* lsm = out;                               // [N, 6]
    float* x1  = out + (size_t)N_NODES * NCLS;      // [N, 16]

    const int NB_N = (N_NODES + 255) / 256;         // 391
    const int NB_E = (N_EDGES + 255) / 256;

    float* W    = (float*)d_ws;
    int*   flag = (int*)d_ws;

    // ---- tier-1 bucket layout (4B words) ----
    int*   bcnt    = (int*)(W + 256);        // 783
    int*   bstart  = (int*)(W + 1152);       // 783
    int*   bcursor = (int*)(W + 2048);       // 782
    float* dinvB   = W + 2944;               // 100000
    float* h1B     = W + 102944;             // 1,600,000  (16B-aligned)
    float* h2p     = W + 1702944;            // 800,000    (16B-aligned)
    uint2* abuf    = (uint2*)(W + 2502944);  // 3.2M uint2 (8B-aligned)
    const size_t NEED = (size_t)8902944 * 4;        // ~35.6 MB

    if (ws_size >= NEED) {
        hipMemsetAsync(bcnt, 0, (NBUK + 1) * 4, stream);
        k_detect<<<1, 64, 0, stream>>>(ei, flag);
        k_bhist <<<NBLK_A, 256, 0, stream>>>(ei, flag, bcnt);
        k_bscan <<<1, 1024, 0, stream>>>(bcnt, bstart, bcursor);
        k_bscat <<<NBLK_A, 256, 0, stream>>>(ei, ew, flag, bcursor, abuf);
        k_degB  <<<NBUK, 256, 0, stream>>>(bstart, abuf, dinvB);
        k_gemm1 <<<NB_N, 256, 0, stream>>>(x, W1, h1B);
        k_agg1  <<<NBUK, 256, 0, stream>>>(bstart, abuf, dinvB, h1B, b1, W2, x1, h2p);
        k_agg2  <<<NBUK, 256, 0, stream>>>(bstart, abuf, dinvB, h2p, b2, lsm);
    } else {
        float* deg  = W + 1024;
        float* fh1  = W + 101376;
        float* fh2  = fh1 + (size_t)N_NODES * HIDDEN;
        float* agg2 = fh2 + (size_t)N_NODES * NCLS;
        hipMemsetAsync(x1,   0, (size_t)N_NODES * HIDDEN * sizeof(float), stream);
        hipMemsetAsync(agg2, 0, (size_t)N_NODES * NCLS   * sizeof(float), stream);
        k_detect <<<1, 64, 0, stream>>>(ei, flag);
        k_initdeg<<<NB_N, 256, 0, stream>>>(deg);
        k_degacc <<<NB_E, 256, 0, stream>>>(ei, ew, flag, deg);
        k_dinv   <<<NB_N, 256, 0, stream>>>(deg);
        k_gemm1  <<<NB_N, 256, 0, stream>>>(x, W1, fh1);
        k_scatter1<<<(N_EDGES * HIDDEN + 255) / 256, 256, 0, stream>>>(ei, ew, flag, deg, fh1, x1);
        k_fin1_gemm2<<<NB_N, 256, 0, stream>>>(b1, W2, deg, fh1, x1, fh2);
        k_scatter2<<<(N_EDGES * NCLS + 255) / 256, 256, 0, stream>>>(ei, ew, flag, deg, fh2, agg2);
        k_final  <<<NB_N, 256, 0, stream>>>(agg2, fh2, deg, b2, lsm);
    }
}

// Round 6
// 338.835 us; speedup vs baseline: 1.9491x; 1.9491x over previous
//
#include <hip/hip_runtime.h>

#define N_NODES 100000
#define N_EDGES 3200000
#define D_FEAT  512
#define HIDDEN  16
#define NCLS    6
#define BSH     7                      // bucket = col >> 7
#define BNODES  128                    // nodes per bucket
#define NBUK    782                    // ceil(N_NODES/128)
#define BCAP    6144                   // LDS bucket capacity (avg 4092, +32 sigma)
#define TILE    8192
#define NBLK_A  391                    // ceil(N_EDGES/TILE)

// ---------- helpers ----------

// edge_index may arrive as int32 (JAX x64 disabled) or int64 (x64 enabled).
// flag==1 means int64 layout (pairs of i32, low word first, little-endian).
__device__ __forceinline__ int eidx(const int* __restrict__ ei, int is64, int pos) {
    return is64 ? ei[2 * (long long)pos] : ei[pos];
}

__global__ void k_detect(const int* __restrict__ ei, int* __restrict__ flag) {
    int v = ei[2 * threadIdx.x + 1];
    unsigned long long b = __ballot(v != 0);
    if (threadIdx.x == 0) flag[0] = (b == 0ULL) ? 1 : 0;
}

// ---------- bucket build ----------

__global__ __launch_bounds__(256)
void k_bhist(const int* __restrict__ ei, const int* __restrict__ flag,
             int* __restrict__ bcnt) {
    __shared__ int lh[NBUK];
    for (int i = threadIdx.x; i < NBUK; i += 256) lh[i] = 0;
    __syncthreads();
    int is64 = flag[0];
    int s = blockIdx.x * TILE, e1 = min(s + TILE, N_EDGES);
    for (int e = s + threadIdx.x; e < e1; e += 256) {
        int c = eidx(ei, is64, N_EDGES + e);
        atomicAdd(&lh[c >> BSH], 1);
    }
    __syncthreads();
    for (int i = threadIdx.x; i < NBUK; i += 256)
        if (lh[i]) atomicAdd(&bcnt[i], lh[i]);
}

// scan of NBUK bucket counts -> bstart (excl, total at [NBUK]) and bcursor
__global__ void k_bscan(const int* __restrict__ bcnt, int* __restrict__ bstart,
                        int* __restrict__ bcursor) {
    __shared__ int s[1024];
    int t = threadIdx.x;
    int v = (t < NBUK) ? bcnt[t] : 0;
    s[t] = v;
    __syncthreads();
    for (int off = 1; off < 1024; off <<= 1) {
        int u = (t >= off) ? s[t - off] : 0;
        __syncthreads();
        s[t] += u;
        __syncthreads();
    }
    int excl = s[t] - v;
    if (t <= NBUK) bstart[t] = excl;
    if (t < NBUK)  bcursor[t] = excl;
}

// scatter edges into bucket-major abuf with block-reserved runs
// pack: x = row | (col&127)<<17  (row < 2^17), y = bits(w)
__global__ __launch_bounds__(256)
void k_bscat(const int* __restrict__ ei, const float* __restrict__ ew,
             const int* __restrict__ flag, int* __restrict__ bcursor,
             uint2* __restrict__ abuf) {
    __shared__ int lh[NBUK];
    __shared__ int lbase[NBUK];
    __shared__ int lcur[NBUK];
    for (int i = threadIdx.x; i < NBUK; i += 256) { lh[i] = 0; lcur[i] = 0; }
    __syncthreads();
    int is64 = flag[0];
    int s = blockIdx.x * TILE, e1 = min(s + TILE, N_EDGES);
    for (int e = s + threadIdx.x; e < e1; e += 256) {
        int c = eidx(ei, is64, N_EDGES + e);
        atomicAdd(&lh[c >> BSH], 1);
    }
    __syncthreads();
    for (int i = threadIdx.x; i < NBUK; i += 256)
        if (lh[i]) lbase[i] = atomicAdd(&bcursor[i], lh[i]);
    __syncthreads();
    for (int e = s + threadIdx.x; e < e1; e += 256) {
        int r = eidx(ei, is64, e);
        int c = eidx(ei, is64, N_EDGES + e);
        float w = ew[e];
        int b = c >> BSH;
        int off = atomicAdd(&lcur[b], 1);
        abuf[lbase[b] + off] = make_uint2((unsigned)r | ((unsigned)(c & (BNODES - 1)) << 17),
                                          __float_as_uint(w));
    }
}

// per-bucket counting sort (LDS-staged): abuf -> eperm {row, w}; emits
// startA (prefix, +[N]=E via node==N_NODES) and dinv. Single abuf read.
__global__ __launch_bounds__(256)
void k_bsort(const int* __restrict__ bstart, const uint2* __restrict__ abuf,
             uint2* __restrict__ eperm, int* __restrict__ startA,
             float* __restrict__ dinv) {
    __shared__ uint2 se[BCAP];                     // 48 KB
    __shared__ int   cnt[BNODES];
    __shared__ int   scn[256];
    __shared__ int   cur[BNODES];
    __shared__ float wsum[BNODES];
    int t = threadIdx.x, b = blockIdx.x;
    int s0 = bstart[b], s1 = bstart[b + 1];
    int nb = s1 - s0;
    if (t < BNODES) { cnt[t] = 0; wsum[t] = 0.0f; }
    __syncthreads();

    bool fits = (nb <= BCAP);
    if (fits) {
        for (int k = t; k < nb; k += 256) {
            uint2 a = abuf[s0 + k];
            se[k] = a;
            int ln = (int)(a.x >> 17);
            atomicAdd(&cnt[ln], 1);
            atomicAdd(&wsum[ln], __uint_as_float(a.y));
        }
    } else {                                        // safe fallback: 2-pass global
        for (int k = t; k < nb; k += 256) {
            uint2 a = abuf[s0 + k];
            int ln = (int)(a.x >> 17);
            atomicAdd(&cnt[ln], 1);
            atomicAdd(&wsum[ln], __uint_as_float(a.y));
        }
    }
    __syncthreads();
    int v = (t < BNODES) ? cnt[t] : 0;
    scn[t] = v;
    __syncthreads();
    for (int off = 1; off < 256; off <<= 1) {
        int u = (t >= off) ? scn[t - off] : 0;
        __syncthreads();
        scn[t] += u;
        __syncthreads();
    }
    int excl = scn[t] - v;
    if (t < BNODES) {
        cur[t] = excl;
        int node = b * BNODES + t;
        if (node <= N_NODES) startA[node] = s0 + excl;
        if (node <  N_NODES) dinv[node] = rsqrtf(1.0f + wsum[t]);
    }
    // also cover startA[N] when it falls past t<BNODES range of last block
    if (b == NBUK - 1 && t == 255) {
        // nodes in last bucket: [b*128, b*128+127]; N_NODES may exceed range end+1
        // handled above when node==N_NODES within t<BNODES; nothing else needed.
    }
    __syncthreads();
    if (fits) {
        for (int k = t; k < nb; k += 256) {
            uint2 a = se[k];
            int ln = (int)(a.x >> 17);
            int off = atomicAdd(&cur[ln], 1);
            eperm[s0 + off] = make_uint2(a.x & 0x1FFFFu, a.y);
        }
    } else {
        for (int k = t; k < nb; k += 256) {
            uint2 a = abuf[s0 + k];
            int ln = (int)(a.x >> 17);
            int off = atomicAdd(&cur[ln], 1);
            eperm[s0 + off] = make_uint2(a.x & 0x1FFFFu, a.y);
        }
    }
}

// ---------- layer 1 transform: h1 = x @ W1 ----------
// Thread-per-row, 16 k-chunks of 32, x tile transposed in LDS (pad 257).
// W1 uniform -> s_load; register double-buffer hides HBM latency.

__global__ __launch_bounds__(256)
void k_gemm1(const float* __restrict__ x, const float* __restrict__ W1g,
             float* __restrict__ h1) {
    __shared__ float xT[32 * 257];
    const int t = threadIdx.x;
    const int row0 = blockIdx.x * 256;
    const int myrow = row0 + t;

    float4 rg[8], rn[8];
#pragma unroll
    for (int p = 0; p < 8; ++p) {
        int f = t + 256 * p;
        int lr = f >> 3, lc = f & 7;
        int gr = min(row0 + lr, N_NODES - 1);
        rg[p] = *(const float4*)(x + (size_t)gr * D_FEAT + 4 * lc);
    }

    float acc[16];
#pragma unroll
    for (int j = 0; j < 16; ++j) acc[j] = 0.0f;

    for (int ch = 0; ch < 16; ++ch) {
        __syncthreads();
#pragma unroll
        for (int p = 0; p < 8; ++p) {
            int f = t + 256 * p;
            int lr = f >> 3, lc = f & 7;
            xT[(4 * lc + 0) * 257 + lr] = rg[p].x;
            xT[(4 * lc + 1) * 257 + lr] = rg[p].y;
            xT[(4 * lc + 2) * 257 + lr] = rg[p].z;
            xT[(4 * lc + 3) * 257 + lr] = rg[p].w;
        }
        if (ch < 15) {
            int k0n = (ch + 1) * 32;
#pragma unroll
            for (int p = 0; p < 8; ++p) {
                int f = t + 256 * p;
                int lr = f >> 3, lc = f & 7;
                int gr = min(row0 + lr, N_NODES - 1);
                rn[p] = *(const float4*)(x + (size_t)gr * D_FEAT + k0n + 4 * lc);
            }
        }
        __syncthreads();
        const int k0 = ch * 32;
#pragma unroll
        for (int k = 0; k < 32; ++k) {
            float xk = xT[k * 257 + t];
            const float* wr = W1g + ((size_t)(k0 + k) << 4);
#pragma unroll
            for (int j = 0; j < 16; ++j) acc[j] = fmaf(xk, wr[j], acc[j]);
        }
#pragma unroll
        for (int p = 0; p < 8; ++p) rg[p] = rn[p];
    }

    if (myrow < N_NODES) {
        float4* o = (float4*)(h1 + (size_t)myrow * HIDDEN);
        o[0] = make_float4(acc[0],  acc[1],  acc[2],  acc[3]);
        o[1] = make_float4(acc[4],  acc[5],  acc[6],  acc[7]);
        o[2] = make_float4(acc[8],  acc[9],  acc[10], acc[11]);
        o[3] = make_float4(acc[12], acc[13], acc[14], acc[15]);
    }
}

// ---------- gather layer 1 (+ bias + self-loop) fused with gemm2 ----------
// 16 lanes per node; packed eperm; unroll-2 independent chains.

__global__ __launch_bounds__(256)
void k_gather1(const int* __restrict__ startA, const uint2* __restrict__ ep,
               const float* __restrict__ dinv, const float* __restrict__ h1,
               const float* __restrict__ b1, const float* __restrict__ W2g,
               float* __restrict__ x1, float* __restrict__ h2p) {
    __shared__ float sW2[HIDDEN * NCLS];
    __shared__ float sv[16][HIDDEN + 1];
    if (threadIdx.x < HIDDEN * NCLS) sW2[threadIdx.x] = W2g[threadIdx.x];
    int ln = threadIdx.x >> 4, j = threadIdx.x & 15;
    int i = blockIdx.x * 16 + ln;
    bool act = (i < N_NODES);
    float v = 0.0f;
    if (act) {
        int s0 = startA[i], n = startA[i + 1] - s0;
        float a0 = 0.0f, a1 = 0.0f;
        int k = 0;
        for (; k + 2 <= n; k += 2) {
            uint2 e0 = ep[s0 + k], e1 = ep[s0 + k + 1];
            int r0 = (int)e0.x, r1 = (int)e1.x;
            a0 = fmaf(__uint_as_float(e0.y) * dinv[r0], h1[(size_t)r0 * HIDDEN + j], a0);
            a1 = fmaf(__uint_as_float(e1.y) * dinv[r1], h1[(size_t)r1 * HIDDEN + j], a1);
        }
        if (k < n) {
            uint2 e0 = ep[s0 + k];
            int r0 = (int)e0.x;
            a0 = fmaf(__uint_as_float(e0.y) * dinv[r0], h1[(size_t)r0 * HIDDEN + j], a0);
        }
        float di = dinv[i];
        v = di * (a0 + a1) + di * di * h1[(size_t)i * HIDDEN + j] + b1[j];
        x1[(size_t)i * HIDDEN + j] = v;
    }
    sv[ln][j] = v;
    __syncthreads();
    if (act && j < 8) {
        float a = 0.0f;
        if (j < NCLS) {
#pragma unroll
            for (int kk = 0; kk < HIDDEN; ++kk)
                a = fmaf(sv[ln][kk], sW2[kk * NCLS + j], a);
        }
        h2p[(size_t)i * 8 + j] = a;                // cols 6,7 = 0 pad
    }
}

// ---------- gather layer 2 fused with log_softmax ----------
// 8 lanes per node on padded h2p[N,8] (all lanes active, 32B rows).

__global__ __launch_bounds__(256)
void k_gather2(const int* __restrict__ startA, const uint2* __restrict__ ep,
               const float* __restrict__ dinv, const float* __restrict__ h2p,
               const float* __restrict__ b2, float* __restrict__ out) {
    __shared__ float sv[32][9];
    int ln = threadIdx.x >> 3, j = threadIdx.x & 7;
    int i = blockIdx.x * 32 + ln;
    bool act = (i < N_NODES);
    float v = 0.0f;
    if (act) {
        int s0 = startA[i], n = startA[i + 1] - s0;
        float a0 = 0.0f, a1 = 0.0f;
        int k = 0;
        for (; k + 2 <= n; k += 2) {
            uint2 e0 = ep[s0 + k], e1 = ep[s0 + k + 1];
            int r0 = (int)e0.x, r1 = (int)e1.x;
            a0 = fmaf(__uint_as_float(e0.y) * dinv[r0], h2p[(size_t)r0 * 8 + j], a0);
            a1 = fmaf(__uint_as_float(e1.y) * dinv[r1], h2p[(size_t)r1 * 8 + j], a1);
        }
        if (k < n) {
            uint2 e0 = ep[s0 + k];
            int r0 = (int)e0.x;
            a0 = fmaf(__uint_as_float(e0.y) * dinv[r0], h2p[(size_t)r0 * 8 + j], a0);
        }
        float di = dinv[i];
        float bj = (j < NCLS) ? b2[j] : 0.0f;
        v = di * (a0 + a1) + di * di * h2p[(size_t)i * 8 + j] + bj;
    }
    sv[ln][j] = v;
    __syncthreads();
    if (act && j < NCLS) {
        float m = -1e30f;
#pragma unroll
        for (int c = 0; c < NCLS; ++c) m = fmaxf(m, sv[ln][c]);
        float ssum = 0.0f;
#pragma unroll
        for (int c = 0; c < NCLS; ++c) ssum += __expf(sv[ln][c] - m);
        out[(size_t)i * NCLS + j] = v - m - __logf(ssum);
    }
}

// ---------- tier-3 atomic fallback kernels (small ws) ----------

__global__ void k_initdeg(float* __restrict__ deg) {
    int i = blockIdx.x * 256 + threadIdx.x;
    if (i < N_NODES) deg[i] = 1.0f;
}

__global__ void k_degacc(const int* __restrict__ ei, const float* __restrict__ w,
                         const int* __restrict__ flag, float* __restrict__ deg) {
    int e = blockIdx.x * 256 + threadIdx.x;
    if (e >= N_EDGES) return;
    int c = eidx(ei, flag[0], N_EDGES + e);
    atomicAdd(&deg[c], w[e]);
}

__global__ void k_dinv(float* __restrict__ deg) {
    int i = blockIdx.x * 256 + threadIdx.x;
    if (i < N_NODES) {
        float d = deg[i];
        deg[i] = (d > 0.0f) ? rsqrtf(d) : 0.0f;
    }
}

__global__ __launch_bounds__(256)
void k_scatter1(const int* __restrict__ ei, const float* __restrict__ w,
                const int* __restrict__ flag, const float* __restrict__ dinv,
                const float* __restrict__ h1, float* __restrict__ agg1) {
    int t = blockIdx.x * 256 + threadIdx.x;
    if (t >= N_EDGES * HIDDEN) return;
    int e = t >> 4, j = t & 15;
    int is64 = flag[0];
    int r = eidx(ei, is64, e);
    int c = eidx(ei, is64, N_EDGES + e);
    float nrm = dinv[r] * w[e] * dinv[c];
    atomicAdd(&agg1[(size_t)c * HIDDEN + j], nrm * h1[(size_t)r * HIDDEN + j]);
}

__global__ void k_fin1_gemm2(const float* __restrict__ b1, const float* __restrict__ W2,
                             const float* __restrict__ dinv, const float* __restrict__ h1,
                             float* __restrict__ x1, float* __restrict__ h2) {
    int i = blockIdx.x * 256 + threadIdx.x;
    if (i >= N_NODES) return;
    float d2 = dinv[i] * dinv[i];
    float v[HIDDEN];
#pragma unroll
    for (int k = 0; k < HIDDEN; ++k)
        v[k] = x1[(size_t)i * HIDDEN + k] + d2 * h1[(size_t)i * HIDDEN + k] + b1[k];
#pragma unroll
    for (int k = 0; k < HIDDEN; ++k)
        x1[(size_t)i * HIDDEN + k] = v[k];
#pragma unroll
    for (int j = 0; j < NCLS; ++j) {
        float a = 0.0f;
#pragma unroll
        for (int k = 0; k < HIDDEN; ++k) a = fmaf(v[k], W2[k * NCLS + j], a);
        h2[(size_t)i * NCLS + j] = a;
    }
}

__global__ __launch_bounds__(256)
void k_scatter2(const int* __restrict__ ei, const float* __restrict__ w,
                const int* __restrict__ flag, const float* __restrict__ dinv,
                const float* __restrict__ h2, float* __restrict__ agg2) {
    int t = blockIdx.x * 256 + threadIdx.x;
    if (t >= N_EDGES * NCLS) return;
    int e = t / NCLS, j = t - e * NCLS;
    int is64 = flag[0];
    int r = eidx(ei, is64, e);
    int c = eidx(ei, is64, N_EDGES + e);
    float nrm = dinv[r] * w[e] * dinv[c];
    atomicAdd(&agg2[(size_t)c * NCLS + j], nrm * h2[(size_t)r * NCLS + j]);
}

__global__ void k_final(const float* __restrict__ agg2, const float* __restrict__ h2,
                        const float* __restrict__ dinv, const float* __restrict__ b2,
                        float* __restrict__ out) {
    int i = blockIdx.x * 256 + threadIdx.x;
    if (i >= N_NODES) return;
    float d2 = dinv[i] * dinv[i];
    float v[NCLS];
    float m = -1e30f;
#pragma unroll
    for (int j = 0; j < NCLS; ++j) {
        v[j] = agg2[(size_t)i * NCLS + j] + d2 * h2[(size_t)i * NCLS + j] + b2[j];
        m = fmaxf(m, v[j]);
    }
    float s = 0.0f;
#pragma unroll
    for (int j = 0; j < NCLS; ++j) s += __expf(v[j] - m);
    float l = __logf(s);
#pragma unroll
    for (int j = 0; j < NCLS; ++j) out[(size_t)i * NCLS + j] = v[j] - m - l;
}

// ---------- launch ----------

extern "C" void kernel_launch(void* const* d_in, const int* in_sizes, int n_in,
                              void* d_out, int out_size, void* d_ws, size_t ws_size,
                              hipStream_t stream) {
    const float* x  = (const float*)d_in[0];
    const float* W1 = (const float*)d_in[1];
    const float* b1 = (const float*)d_in[2];
    const float* W2 = (const float*)d_in[3];
    const float* b2 = (const float*)d_in[4];
    const float* ew = (const float*)d_in[5];
    const int*   ei = (const int*)d_in[6];

    float* out = (float*)d_out;
    float* lsm = out;                               // [N, 6]
    float* x1  = out + (size_t)N_NODES * NCLS;      // [N, 16]

    const int NB_N = (N_NODES + 255) / 256;         // 391
    const int NB_E = (N_EDGES + 255) / 256;

    float* W    = (float*)d_ws;
    int*   flag = (int*)d_ws;

    // ---- tier-1 layout (4B words) ----
    int*   bcnt    = (int*)(W + 256);        // 783
    int*   bstart  = (int*)(W + 1152);       // 783
    int*   bcursor = (int*)(W + 2048);       // 782
    int*   startA  = (int*)(W + 2944);       // 100001 -> ends 102945
    float* dinvB   = W + 102948;             // 100000 -> ends 202948
    uint2* abuf    = (uint2*)(W + 202948);   // 3.2M uint2 -> ends 6602948; aliased:
    float* h1B     = W + 202948;             //   1.6M (written after abuf dies)
    float* h2p     = W + 1802948;            //   800K padded [N,8]
    uint2* eperm   = (uint2*)(W + 6602948);  // 3.2M uint2 -> ends 13002948
    const size_t NEED = (size_t)13002948 * 4;       // ~52.0 MB

    if (ws_size >= NEED) {
        hipMemsetAsync(bcnt, 0, (NBUK + 1) * 4, stream);
        k_detect<<<1, 64, 0, stream>>>(ei, flag);
        k_bhist <<<NBLK_A, 256, 0, stream>>>(ei, flag, bcnt);
        k_bscan <<<1, 1024, 0, stream>>>(bcnt, bstart, bcursor);
        k_bscat <<<NBLK_A, 256, 0, stream>>>(ei, ew, flag, bcursor, abuf);
        k_bsort <<<NBUK, 256, 0, stream>>>(bstart, abuf, eperm, startA, dinvB);
        k_gemm1 <<<NB_N, 256, 0, stream>>>(x, W1, h1B);
        k_gather1<<<(N_NODES + 15) / 16, 256, 0, stream>>>(startA, eperm, dinvB, h1B,
                                                           b1, W2, x1, h2p);
        k_gather2<<<(N_NODES + 31) / 32, 256, 0, stream>>>(startA, eperm, dinvB, h2p,
                                                           b2, lsm);
    } else {
        float* deg  = W + 1024;
        float* fh1  = W + 101376;
        float* fh2  = fh1 + (size_t)N_NODES * HIDDEN;
        float* agg2 = fh2 + (size_t)N_NODES * NCLS;
        hipMemsetAsync(x1,   0, (size_t)N_NODES * HIDDEN * sizeof(float), stream);
        hipMemsetAsync(agg2, 0, (size_t)N_NODES * NCLS   * sizeof(float), stream);
        k_detect <<<1, 64, 0, stream>>>(ei, flag);
        k_initdeg<<<NB_N, 256, 0, stream>>>(deg);
        k_degacc <<<NB_E, 256, 0, stream>>>(ei, ew, flag, deg);
        k_dinv   <<<NB_N, 256, 0, stream>>>(deg);
        k_gemm1  <<<NB_N, 256, 0, stream>>>(x, W1, fh1);
        k_scatter1<<<(N_EDGES * HIDDEN + 255) / 256, 256, 0, stream>>>(ei, ew, flag, deg, fh1, x1);
        k_fin1_gemm2<<<NB_N, 256, 0, stream>>>(b1, W2, deg, fh1, x1, fh2);
        k_scatter2<<<(N_EDGES * NCLS + 255) / 256, 256, 0, stream>>>(ei, ew, flag, deg, fh2, agg2);
        k_final  <<<NB_N, 256, 0, stream>>>(agg2, fh2, deg, b2, lsm);
    }
}

// Round 7
// 319.899 us; speedup vs baseline: 2.0645x; 1.0592x over previous
//
#include <hip/hip_runtime.h>

#define N_NODES 100000
#define N_EDGES 3200000
#define D_FEAT  512
#define HIDDEN  16
#define NCLS    6
#define BSH     7                      // bucket = col >> 7
#define BNODES  128                    // nodes per bucket
#define NBUK    782                    // ceil(N_NODES/128)
#define BCAP    6144                   // LDS bucket capacity (avg 4092, +32 sigma)
#define TILE    8192
#define NBLK_A  391                    // ceil(N_EDGES/TILE)

// ---------- helpers ----------

// edge_index may arrive as int32 (JAX x64 disabled) or int64 (x64 enabled).
// flag==1 means int64 layout (pairs of i32, low word first, little-endian).
__device__ __forceinline__ int eidx(const int* __restrict__ ei, int is64, int pos) {
    return is64 ? ei[2 * (long long)pos] : ei[pos];
}

__global__ void k_detect(const int* __restrict__ ei, int* __restrict__ flag) {
    int v = ei[2 * threadIdx.x + 1];
    unsigned long long b = __ballot(v != 0);
    if (threadIdx.x == 0) flag[0] = (b == 0ULL) ? 1 : 0;
}

// ---------- bucket build ----------

__global__ __launch_bounds__(256)
void k_bhist(const int* __restrict__ ei, const int* __restrict__ flag,
             int* __restrict__ bcnt) {
    __shared__ int lh[NBUK];
    for (int i = threadIdx.x; i < NBUK; i += 256) lh[i] = 0;
    __syncthreads();
    int is64 = flag[0];
    int s = blockIdx.x * TILE, e1 = min(s + TILE, N_EDGES);
    for (int e = s + threadIdx.x; e < e1; e += 256) {
        int c = eidx(ei, is64, N_EDGES + e);
        atomicAdd(&lh[c >> BSH], 1);
    }
    __syncthreads();
    for (int i = threadIdx.x; i < NBUK; i += 256)
        if (lh[i]) atomicAdd(&bcnt[i], lh[i]);
}

// scan of NBUK bucket counts -> bstart (excl, total at [NBUK]) and bcursor
__global__ void k_bscan(const int* __restrict__ bcnt, int* __restrict__ bstart,
                        int* __restrict__ bcursor) {
    __shared__ int s[1024];
    int t = threadIdx.x;
    int v = (t < NBUK) ? bcnt[t] : 0;
    s[t] = v;
    __syncthreads();
    for (int off = 1; off < 1024; off <<= 1) {
        int u = (t >= off) ? s[t - off] : 0;
        __syncthreads();
        s[t] += u;
        __syncthreads();
    }
    int excl = s[t] - v;
    if (t <= NBUK) bstart[t] = excl;
    if (t < NBUK)  bcursor[t] = excl;
}

// scatter edges into bucket-major abuf with block-reserved runs
// pack: x = row | (col&127)<<17  (row < 2^17), y = bits(w)
__global__ __launch_bounds__(256)
void k_bscat(const int* __restrict__ ei, const float* __restrict__ ew,
             const int* __restrict__ flag, int* __restrict__ bcursor,
             uint2* __restrict__ abuf) {
    __shared__ int lh[NBUK];
    __shared__ int lbase[NBUK];
    __shared__ int lcur[NBUK];
    for (int i = threadIdx.x; i < NBUK; i += 256) { lh[i] = 0; lcur[i] = 0; }
    __syncthreads();
    int is64 = flag[0];
    int s = blockIdx.x * TILE, e1 = min(s + TILE, N_EDGES);
    for (int e = s + threadIdx.x; e < e1; e += 256) {
        int c = eidx(ei, is64, N_EDGES + e);
        atomicAdd(&lh[c >> BSH], 1);
    }
    __syncthreads();
    for (int i = threadIdx.x; i < NBUK; i += 256)
        if (lh[i]) lbase[i] = atomicAdd(&bcursor[i], lh[i]);
    __syncthreads();
    for (int e = s + threadIdx.x; e < e1; e += 256) {
        int r = eidx(ei, is64, e);
        int c = eidx(ei, is64, N_EDGES + e);
        float w = ew[e];
        int b = c >> BSH;
        int off = atomicAdd(&lcur[b], 1);
        abuf[lbase[b] + off] = make_uint2((unsigned)r | ((unsigned)(c & (BNODES - 1)) << 17),
                                          __float_as_uint(w));
    }
}

// per-bucket degree -> dinv  (deg = 1 self-loop + sum w); runs BEFORE bsort
__global__ __launch_bounds__(256)
void k_degB(const int* __restrict__ bstart, const uint2* __restrict__ abuf,
            float* __restrict__ dinv) {
    __shared__ float wsum[BNODES];
    int t = threadIdx.x, b = blockIdx.x;
    if (t < BNODES) wsum[t] = 0.0f;
    __syncthreads();
    int s0 = bstart[b], s1 = bstart[b + 1];
    for (int k = s0 + t; k < s1; k += 256) {
        uint2 a = abuf[k];
        atomicAdd(&wsum[a.x >> 17], __uint_as_float(a.y));
    }
    __syncthreads();
    int node = b * BNODES + t;
    if (t < BNODES && node < N_NODES) dinv[node] = rsqrtf(1.0f + wsum[t]);
}

// per-bucket counting sort (LDS-staged): abuf -> eperm {row, w*dinv[row]};
// emits startA (prefix, +[N]=E). Requires dinv complete (k_degB).
__global__ __launch_bounds__(256)
void k_bsort(const int* __restrict__ bstart, const uint2* __restrict__ abuf,
             const float* __restrict__ dinv, uint2* __restrict__ eperm,
             int* __restrict__ startA) {
    __shared__ uint2 se[BCAP];                     // 48 KB
    __shared__ int   cnt[BNODES];
    __shared__ int   scn[256];
    __shared__ int   cur[BNODES];
    int t = threadIdx.x, b = blockIdx.x;
    int s0 = bstart[b], s1 = bstart[b + 1];
    int nb = s1 - s0;
    if (t < BNODES) cnt[t] = 0;
    __syncthreads();

    bool fits = (nb <= BCAP);
    if (fits) {
        for (int k = t; k < nb; k += 256) {
            uint2 a = abuf[s0 + k];
            se[k] = a;
            atomicAdd(&cnt[a.x >> 17], 1);
        }
    } else {
        for (int k = t; k < nb; k += 256) {
            uint2 a = abuf[s0 + k];
            atomicAdd(&cnt[a.x >> 17], 1);
        }
    }
    __syncthreads();
    int v = (t < BNODES) ? cnt[t] : 0;
    scn[t] = v;
    __syncthreads();
    for (int off = 1; off < 256; off <<= 1) {
        int u = (t >= off) ? scn[t - off] : 0;
        __syncthreads();
        scn[t] += u;
        __syncthreads();
    }
    int excl = scn[t] - v;
    if (t < BNODES) {
        cur[t] = excl;
        int node = b * BNODES + t;
        if (node <= N_NODES) startA[node] = s0 + excl;
    }
    __syncthreads();
    if (fits) {
        for (int k = t; k < nb; k += 256) {
            uint2 a = se[k];
            int ln = (int)(a.x >> 17);
            int r  = (int)(a.x & 0x1FFFFu);
            float wn = __uint_as_float(a.y) * dinv[r];
            int off = atomicAdd(&cur[ln], 1);
            eperm[s0 + off] = make_uint2((unsigned)r, __float_as_uint(wn));
        }
    } else {
        for (int k = t; k < nb; k += 256) {
            uint2 a = abuf[s0 + k];
            int ln = (int)(a.x >> 17);
            int r  = (int)(a.x & 0x1FFFFu);
            float wn = __uint_as_float(a.y) * dinv[r];
            int off = atomicAdd(&cur[ln], 1);
            eperm[s0 + off] = make_uint2((unsigned)r, __float_as_uint(wn));
        }
    }
}

// ---------- layer 1 transform: h1 = x @ W1 ----------
// Thread-per-row, 16 k-chunks of 32, x tile transposed in LDS (pad 257).
// W1 uniform -> s_load; register double-buffer hides HBM latency.

__global__ __launch_bounds__(256)
void k_gemm1(const float* __restrict__ x, const float* __restrict__ W1g,
             float* __restrict__ h1) {
    __shared__ float xT[32 * 257];
    const int t = threadIdx.x;
    const int row0 = blockIdx.x * 256;
    const int myrow = row0 + t;

    float4 rg[8], rn[8];
#pragma unroll
    for (int p = 0; p < 8; ++p) {
        int f = t + 256 * p;
        int lr = f >> 3, lc = f & 7;
        int gr = min(row0 + lr, N_NODES - 1);
        rg[p] = *(const float4*)(x + (size_t)gr * D_FEAT + 4 * lc);
    }

    float acc[16];
#pragma unroll
    for (int j = 0; j < 16; ++j) acc[j] = 0.0f;

    for (int ch = 0; ch < 16; ++ch) {
        __syncthreads();
#pragma unroll
        for (int p = 0; p < 8; ++p) {
            int f = t + 256 * p;
            int lr = f >> 3, lc = f & 7;
            xT[(4 * lc + 0) * 257 + lr] = rg[p].x;
            xT[(4 * lc + 1) * 257 + lr] = rg[p].y;
            xT[(4 * lc + 2) * 257 + lr] = rg[p].z;
            xT[(4 * lc + 3) * 257 + lr] = rg[p].w;
        }
        if (ch < 15) {
            int k0n = (ch + 1) * 32;
#pragma unroll
            for (int p = 0; p < 8; ++p) {
                int f = t + 256 * p;
                int lr = f >> 3, lc = f & 7;
                int gr = min(row0 + lr, N_NODES - 1);
                rn[p] = *(const float4*)(x + (size_t)gr * D_FEAT + k0n + 4 * lc);
            }
        }
        __syncthreads();
        const int k0 = ch * 32;
#pragma unroll
        for (int k = 0; k < 32; ++k) {
            float xk = xT[k * 257 + t];
            const float* wr = W1g + ((size_t)(k0 + k) << 4);
#pragma unroll
            for (int j = 0; j < 16; ++j) acc[j] = fmaf(xk, wr[j], acc[j]);
        }
#pragma unroll
        for (int p = 0; p < 8; ++p) rg[p] = rn[p];
    }

    if (myrow < N_NODES) {
        float4* o = (float4*)(h1 + (size_t)myrow * HIDDEN);
        o[0] = make_float4(acc[0],  acc[1],  acc[2],  acc[3]);
        o[1] = make_float4(acc[4],  acc[5],  acc[6],  acc[7]);
        o[2] = make_float4(acc[8],  acc[9],  acc[10], acc[11]);
        o[3] = make_float4(acc[12], acc[13], acc[14], acc[15]);
    }
}

// ---------- gather layer 1 (+ bias + self-loop) fused with gemm2 ----------
// 16 lanes/node = 4 edge-strides (es) x 4 float4-slices (fs). eperm.y already
// holds w*dinv[row]. shfl_xor(4,8) reduces es; gemm2 via LDS tile.

__global__ __launch_bounds__(256)
void k_gather1(const int* __restrict__ startA, const uint2* __restrict__ ep,
               const float* __restrict__ dinv, const float* __restrict__ h1,
               const float* __restrict__ b1, const float* __restrict__ W2g,
               float* __restrict__ x1, float* __restrict__ h2p) {
    __shared__ float sW2[HIDDEN * NCLS];
    __shared__ float sv[16][HIDDEN + 1];
    int t = threadIdx.x;
    if (t < HIDDEN * NCLS) sW2[t] = W2g[t];
    int ln = t >> 4, es = (t >> 2) & 3, fs = t & 3;
    int i = blockIdx.x * 16 + ln;
    bool act = (i < N_NODES);
    float4 a = make_float4(0.0f, 0.0f, 0.0f, 0.0f);
    if (act) {
        int s0 = startA[i], n = startA[i + 1] - s0;
        for (int k = es; k < n; k += 4) {
            uint2 e0 = ep[s0 + k];
            float wn = __uint_as_float(e0.y);
            float4 h = *(const float4*)(h1 + ((size_t)e0.x << 4) + 4 * fs);
            a.x = fmaf(wn, h.x, a.x);
            a.y = fmaf(wn, h.y, a.y);
            a.z = fmaf(wn, h.z, a.z);
            a.w = fmaf(wn, h.w, a.w);
        }
    }
    a.x += __shfl_xor(a.x, 4); a.y += __shfl_xor(a.y, 4);
    a.z += __shfl_xor(a.z, 4); a.w += __shfl_xor(a.w, 4);
    a.x += __shfl_xor(a.x, 8); a.y += __shfl_xor(a.y, 8);
    a.z += __shfl_xor(a.z, 8); a.w += __shfl_xor(a.w, 8);
    if (act && es == 0) {
        float di = dinv[i], d2 = di * di;
        const float* h1r = h1 + (size_t)i * HIDDEN + 4 * fs;
        const float* b1r = b1 + 4 * fs;
        float v0 = di * a.x + d2 * h1r[0] + b1r[0];
        float v1 = di * a.y + d2 * h1r[1] + b1r[1];
        float v2 = di * a.z + d2 * h1r[2] + b1r[2];
        float v3 = di * a.w + d2 * h1r[3] + b1r[3];
        *(float4*)(x1 + (size_t)i * HIDDEN + 4 * fs) = make_float4(v0, v1, v2, v3);
        sv[ln][4 * fs + 0] = v0; sv[ln][4 * fs + 1] = v1;
        sv[ln][4 * fs + 2] = v2; sv[ln][4 * fs + 3] = v3;
    }
    __syncthreads();
    int j = t & 15;
    if (act && j < 8) {
        float acc2 = 0.0f;
        if (j < NCLS) {
#pragma unroll
            for (int kk = 0; kk < HIDDEN; ++kk)
                acc2 = fmaf(sv[ln][kk], sW2[kk * NCLS + j], acc2);
        }
        h2p[(size_t)i * 8 + j] = acc2;             // cols 6,7 = 0 pad
    }
}

// ---------- gather layer 2 fused with log_softmax ----------
// 16 lanes/node = 8 edge-strides x 2 float4-slices on padded h2p[N,8].

__global__ __launch_bounds__(256)
void k_gather2(const int* __restrict__ startA, const uint2* __restrict__ ep,
               const float* __restrict__ dinv, const float* __restrict__ h2p,
               const float* __restrict__ b2, float* __restrict__ out) {
    __shared__ float sv[16][9];
    int t = threadIdx.x;
    int ln = t >> 4, es = (t >> 1) & 7, fs = t & 1;
    int i = blockIdx.x * 16 + ln;
    bool act = (i < N_NODES);
    float4 a = make_float4(0.0f, 0.0f, 0.0f, 0.0f);
    if (act) {
        int s0 = startA[i], n = startA[i + 1] - s0;
        for (int k = es; k < n; k += 8) {
            uint2 e0 = ep[s0 + k];
            float wn = __uint_as_float(e0.y);
            float4 h = *(const float4*)(h2p + ((size_t)e0.x << 3) + 4 * fs);
            a.x = fmaf(wn, h.x, a.x);
            a.y = fmaf(wn, h.y, a.y);
            a.z = fmaf(wn, h.z, a.z);
            a.w = fmaf(wn, h.w, a.w);
        }
    }
    a.x += __shfl_xor(a.x, 2); a.y += __shfl_xor(a.y, 2);
    a.z += __shfl_xor(a.z, 2); a.w += __shfl_xor(a.w, 2);
    a.x += __shfl_xor(a.x, 4); a.y += __shfl_xor(a.y, 4);
    a.z += __shfl_xor(a.z, 4); a.w += __shfl_xor(a.w, 4);
    a.x += __shfl_xor(a.x, 8); a.y += __shfl_xor(a.y, 8);
    a.z += __shfl_xor(a.z, 8); a.w += __shfl_xor(a.w, 8);
    if (act && es == 0) {
        float di = dinv[i], d2 = di * di;
        const float* hr = h2p + (size_t)i * 8 + 4 * fs;
        int c0 = 4 * fs;
        float v0 = di * a.x + d2 * hr[0] + ((c0 + 0) < NCLS ? b2[c0 + 0] : 0.0f);
        float v1 = di * a.y + d2 * hr[1] + ((c0 + 1) < NCLS ? b2[c0 + 1] : 0.0f);
        float v2 = di * a.z + d2 * hr[2] + ((c0 + 2) < NCLS ? b2[c0 + 2] : 0.0f);
        float v3 = di * a.w + d2 * hr[3] + ((c0 + 3) < NCLS ? b2[c0 + 3] : 0.0f);
        sv[ln][c0 + 0] = v0; sv[ln][c0 + 1] = v1;
        sv[ln][c0 + 2] = v2; sv[ln][c0 + 3] = v3;
    }
    __syncthreads();
    int j = t & 15;
    if (act && j < NCLS) {
        float m = -1e30f;
#pragma unroll
        for (int c = 0; c < NCLS; ++c) m = fmaxf(m, sv[ln][c]);
        float ssum = 0.0f;
#pragma unroll
        for (int c = 0; c < NCLS; ++c) ssum += __expf(sv[ln][c] - m);
        out[(size_t)i * NCLS + j] = sv[ln][j] - m - __logf(ssum);
    }
}

// ---------- tier-3 atomic fallback kernels (small ws) ----------

__global__ void k_initdeg(float* __restrict__ deg) {
    int i = blockIdx.x * 256 + threadIdx.x;
    if (i < N_NODES) deg[i] = 1.0f;
}

__global__ void k_degacc(const int* __restrict__ ei, const float* __restrict__ w,
                         const int* __restrict__ flag, float* __restrict__ deg) {
    int e = blockIdx.x * 256 + threadIdx.x;
    if (e >= N_EDGES) return;
    int c = eidx(ei, flag[0], N_EDGES + e);
    atomicAdd(&deg[c], w[e]);
}

__global__ void k_dinv(float* __restrict__ deg) {
    int i = blockIdx.x * 256 + threadIdx.x;
    if (i < N_NODES) {
        float d = deg[i];
        deg[i] = (d > 0.0f) ? rsqrtf(d) : 0.0f;
    }
}

__global__ __launch_bounds__(256)
void k_scatter1(const int* __restrict__ ei, const float* __restrict__ w,
                const int* __restrict__ flag, const float* __restrict__ dinv,
                const float* __restrict__ h1, float* __restrict__ agg1) {
    int t = blockIdx.x * 256 + threadIdx.x;
    if (t >= N_EDGES * HIDDEN) return;
    int e = t >> 4, j = t & 15;
    int is64 = flag[0];
    int r = eidx(ei, is64, e);
    int c = eidx(ei, is64, N_EDGES + e);
    float nrm = dinv[r] * w[e] * dinv[c];
    atomicAdd(&agg1[(size_t)c * HIDDEN + j], nrm * h1[(size_t)r * HIDDEN + j]);
}

__global__ void k_fin1_gemm2(const float* __restrict__ b1, const float* __restrict__ W2,
                             const float* __restrict__ dinv, const float* __restrict__ h1,
                             float* __restrict__ x1, float* __restrict__ h2) {
    int i = blockIdx.x * 256 + threadIdx.x;
    if (i >= N_NODES) return;
    float d2 = dinv[i] * dinv[i];
    float v[HIDDEN];
#pragma unroll
    for (int k = 0; k < HIDDEN; ++k)
        v[k] = x1[(size_t)i * HIDDEN + k] + d2 * h1[(size_t)i * HIDDEN + k] + b1[k];
#pragma unroll
    for (int k = 0; k < HIDDEN; ++k)
        x1[(size_t)i * HIDDEN + k] = v[k];
#pragma unroll
    for (int j = 0; j < NCLS; ++j) {
        float a = 0.0f;
#pragma unroll
        for (int k = 0; k < HIDDEN; ++k) a = fmaf(v[k], W2[k * NCLS + j], a);
        h2[(size_t)i * NCLS + j] = a;
    }
}

__global__ __launch_bounds__(256)
void k_scatter2(const int* __restrict__ ei, const float* __restrict__ w,
                const int* __restrict__ flag, const float* __restrict__ dinv,
                const float* __restrict__ h2, float* __restrict__ agg2) {
    int t = blockIdx.x * 256 + threadIdx.x;
    if (t >= N_EDGES * NCLS) return;
    int e = t / NCLS, j = t - e * NCLS;
    int is64 = flag[0];
    int r = eidx(ei, is64, e);
    int c = eidx(ei, is64, N_EDGES + e);
    float nrm = dinv[r] * w[e] * dinv[c];
    atomicAdd(&agg2[(size_t)c * NCLS + j], nrm * h2[(size_t)r * NCLS + j]);
}

__global__ void k_final(const float* __restrict__ agg2, const float* __restrict__ h2,
                        const float* __restrict__ dinv, const float* __restrict__ b2,
                        float* __restrict__ out) {
    int i = blockIdx.x * 256 + threadIdx.x;
    if (i >= N_NODES) return;
    float d2 = dinv[i] * dinv[i];
    float v[NCLS];
    float m = -1e30f;
#pragma unroll
    for (int j = 0; j < NCLS; ++j) {
        v[j] = agg2[(size_t)i * NCLS + j] + d2 * h2[(size_t)i * NCLS + j] + b2[j];
        m = fmaxf(m, v[j]);
    }
    float s = 0.0f;
#pragma unroll
    for (int j = 0; j < NCLS; ++j) s += __expf(v[j] - m);
    float l = __logf(s);
#pragma unroll
    for (int j = 0; j < NCLS; ++j) out[(size_t)i * NCLS + j] = v[j] - m - l;
}

// ---------- launch ----------

extern "C" void kernel_launch(void* const* d_in, const int* in_sizes, int n_in,
                              void* d_out, int out_size, void* d_ws, size_t ws_size,
                              hipStream_t stream) {
    const float* x  = (const float*)d_in[0];
    const float* W1 = (const float*)d_in[1];
    const float* b1 = (const float*)d_in[2];
    const float* W2 = (const float*)d_in[3];
    const float* b2 = (const float*)d_in[4];
    const float* ew = (const float*)d_in[5];
    const int*   ei = (const int*)d_in[6];

    float* out = (float*)d_out;
    float* lsm = out;                               // [N, 6]
    float* x1  = out + (size_t)N_NODES * NCLS;      // [N, 16]

    const int NB_N = (N_NODES + 255) / 256;         // 391
    const int NB_E = (N_EDGES + 255) / 256;

    float* W    = (float*)d_ws;
    int*   flag = (int*)d_ws;

    // ---- tier-1 layout (4B words) ----
    int*   bcnt    = (int*)(W + 256);        // 783
    int*   bstart  = (int*)(W + 1152);       // 783
    int*   bcursor = (int*)(W + 2048);       // 782
    int*   startA  = (int*)(W + 2944);       // 100001 -> ends 102945
    float* dinvB   = W + 102948;             // 100000 -> ends 202948
    uint2* abuf    = (uint2*)(W + 202948);   // 3.2M uint2 -> ends 6602948; aliased:
    float* h1B     = W + 202948;             //   1.6M (written after abuf dies)
    float* h2p     = W + 1802948;            //   800K padded [N,8]
    uint2* eperm   = (uint2*)(W + 6602948);  // 3.2M uint2 -> ends 13002948
    const size_t NEED = (size_t)13002948 * 4;       // ~52.0 MB

    if (ws_size >= NEED) {
        hipMemsetAsync(bcnt, 0, (NBUK + 1) * 4, stream);
        k_detect<<<1, 64, 0, stream>>>(ei, flag);
        k_bhist <<<NBLK_A, 256, 0, stream>>>(ei, flag, bcnt);
        k_bscan <<<1, 1024, 0, stream>>>(bcnt, bstart, bcursor);
        k_bscat <<<NBLK_A, 256, 0, stream>>>(ei, ew, flag, bcursor, abuf);
        k_degB  <<<NBUK, 256, 0, stream>>>(bstart, abuf, dinvB);
        k_bsort <<<NBUK, 256, 0, stream>>>(bstart, abuf, dinvB, eperm, startA);
        k_gemm1 <<<NB_N, 256, 0, stream>>>(x, W1, h1B);
        k_gather1<<<(N_NODES + 15) / 16, 256, 0, stream>>>(startA, eperm, dinvB, h1B,
                                                           b1, W2, x1, h2p);
        k_gather2<<<(N_NODES + 15) / 16, 256, 0, stream>>>(startA, eperm, dinvB, h2p,
                                                           b2, lsm);
    } else {
        float* deg  = W + 1024;
        float* fh1  = W + 101376;
        float* fh2  = fh1 + (size_t)N_NODES * HIDDEN;
        float* agg2 = fh2 + (size_t)N_NODES * NCLS;
        hipMemsetAsync(x1,   0, (size_t)N_NODES * HIDDEN * sizeof(float), stream);
        hipMemsetAsync(agg2, 0, (size_t)N_NODES * NCLS   * sizeof(float), stream);
        k_detect <<<1, 64, 0, stream>>>(ei, flag);
        k_initdeg<<<NB_N, 256, 0, stream>>>(deg);
        k_degacc <<<NB_E, 256, 0, stream>>>(ei, ew, flag, deg);
        k_dinv   <<<NB_N, 256, 0, stream>>>(deg);
        k_gemm1  <<<NB_N, 256, 0, stream>>>(x, W1, fh1);
        k_scatter1<<<(N_EDGES * HIDDEN + 255) / 256, 256, 0, stream>>>(ei, ew, flag, deg, fh1, x1);
        k_fin1_gemm2<<<NB_N, 256, 0, stream>>>(b1, W2, deg, fh1, x1, fh2);
        k_scatter2<<<(N_EDGES * NCLS + 255) / 256, 256, 0, stream>>>(ei, ew, flag, deg, fh2, agg2);
        k_final  <<<NB_N, 256, 0, stream>>>(agg2, fh2, deg, b2, lsm);
    }
}

// Round 8
// 308.247 us; speedup vs baseline: 2.1425x; 1.0378x over previous
//
#include <hip/hip_runtime.h>

#define N_NODES 100000
#define N_EDGES 3200000
#define D_FEAT  512
#define HIDDEN  16
#define NCLS    6
#define BSH     7                      // bucket = col >> 7
#define BNODES  128                    // nodes per bucket
#define NBUK    782                    // ceil(N_NODES/128)
#define BCAP    6144                   // LDS bucket capacity (avg 4092, +32 sigma)
#define NBLK_A  512                    // build blocks: exactly 2 per CU
#define TILE    6250                   // ceil(N_EDGES/NBLK_A)

// ---------- helpers ----------

// edge_index may arrive as int32 (JAX x64 disabled) or int64 (x64 enabled).
// flag==1 means int64 layout (pairs of i32, low word first, little-endian).
__device__ __forceinline__ int eidx(const int* __restrict__ ei, int is64, int pos) {
    return is64 ? ei[2 * (long long)pos] : ei[pos];
}

__global__ void k_detect(const int* __restrict__ ei, int* __restrict__ flag) {
    int v = ei[2 * threadIdx.x + 1];
    unsigned long long b = __ballot(v != 0);
    if (threadIdx.x == 0) flag[0] = (b == 0ULL) ? 1 : 0;
}

// ---------- bucket build ----------

__global__ __launch_bounds__(256)
void k_bhist(const int* __restrict__ ei, const int* __restrict__ flag,
             int* __restrict__ bcnt) {
    __shared__ int lh[NBUK];
    for (int i = threadIdx.x; i < NBUK; i += 256) lh[i] = 0;
    __syncthreads();
    int is64 = flag[0];
    int s = blockIdx.x * TILE, e1 = min(s + TILE, N_EDGES);
    for (int e = s + threadIdx.x; e < e1; e += 256) {
        int c = eidx(ei, is64, N_EDGES + e);
        atomicAdd(&lh[c >> BSH], 1);
    }
    __syncthreads();
    for (int i = threadIdx.x; i < NBUK; i += 256)
        if (lh[i]) atomicAdd(&bcnt[i], lh[i]);
}

// scan of NBUK bucket counts -> bstart (excl, total at [NBUK]) and bcursor
__global__ void k_bscan(const int* __restrict__ bcnt, int* __restrict__ bstart,
                        int* __restrict__ bcursor) {
    __shared__ int s[1024];
    int t = threadIdx.x;
    int v = (t < NBUK) ? bcnt[t] : 0;
    s[t] = v;
    __syncthreads();
    for (int off = 1; off < 1024; off <<= 1) {
        int u = (t >= off) ? s[t - off] : 0;
        __syncthreads();
        s[t] += u;
        __syncthreads();
    }
    int excl = s[t] - v;
    if (t <= NBUK) bstart[t] = excl;
    if (t < NBUK)  bcursor[t] = excl;
}

// scatter edges into bucket-major abuf with block-reserved runs
// pack: x = row | (col&127)<<17  (row < 2^17), y = bits(w)
__global__ __launch_bounds__(256)
void k_bscat(const int* __restrict__ ei, const float* __restrict__ ew,
             const int* __restrict__ flag, int* __restrict__ bcursor,
             uint2* __restrict__ abuf) {
    __shared__ int lh[NBUK];
    __shared__ int lbase[NBUK];
    __shared__ int lcur[NBUK];
    for (int i = threadIdx.x; i < NBUK; i += 256) { lh[i] = 0; lcur[i] = 0; }
    __syncthreads();
    int is64 = flag[0];
    int s = blockIdx.x * TILE, e1 = min(s + TILE, N_EDGES);
    for (int e = s + threadIdx.x; e < e1; e += 256) {
        int c = eidx(ei, is64, N_EDGES + e);
        atomicAdd(&lh[c >> BSH], 1);
    }
    __syncthreads();
    for (int i = threadIdx.x; i < NBUK; i += 256)
        if (lh[i]) lbase[i] = atomicAdd(&bcursor[i], lh[i]);
    __syncthreads();
    for (int e = s + threadIdx.x; e < e1; e += 256) {
        int r = eidx(ei, is64, e);
        int c = eidx(ei, is64, N_EDGES + e);
        float w = ew[e];
        int b = c >> BSH;
        int off = atomicAdd(&lcur[b], 1);
        abuf[lbase[b] + off] = make_uint2((unsigned)r | ((unsigned)(c & (BNODES - 1)) << 17),
                                          __float_as_uint(w));
    }
}

// per-bucket degree -> dinv  (deg = 1 self-loop + sum w); runs BEFORE bsort
__global__ __launch_bounds__(256)
void k_degB(const int* __restrict__ bstart, const uint2* __restrict__ abuf,
            float* __restrict__ dinv) {
    __shared__ float wsum[BNODES];
    int t = threadIdx.x, b = blockIdx.x;
    if (t < BNODES) wsum[t] = 0.0f;
    __syncthreads();
    int s0 = bstart[b], s1 = bstart[b + 1];
    for (int k = s0 + t; k < s1; k += 256) {
        uint2 a = abuf[k];
        atomicAdd(&wsum[a.x >> 17], __uint_as_float(a.y));
    }
    __syncthreads();
    int node = b * BNODES + t;
    if (t < BNODES && node < N_NODES) dinv[node] = rsqrtf(1.0f + wsum[t]);
}

// per-bucket counting sort (LDS-staged): abuf -> eperm {row, w*dinv[row]};
// emits startA (prefix, +[N]=E). Requires dinv complete (k_degB).
__global__ __launch_bounds__(256)
void k_bsort(const int* __restrict__ bstart, const uint2* __restrict__ abuf,
             const float* __restrict__ dinv, uint2* __restrict__ eperm,
             int* __restrict__ startA) {
    __shared__ uint2 se[BCAP];                     // 48 KB
    __shared__ int   cnt[BNODES];
    __shared__ int   scn[256];
    __shared__ int   cur[BNODES];
    int t = threadIdx.x, b = blockIdx.x;
    int s0 = bstart[b], s1 = bstart[b + 1];
    int nb = s1 - s0;
    if (t < BNODES) cnt[t] = 0;
    __syncthreads();

    bool fits = (nb <= BCAP);
    if (fits) {
        for (int k = t; k < nb; k += 256) {
            uint2 a = abuf[s0 + k];
            se[k] = a;
            atomicAdd(&cnt[a.x >> 17], 1);
        }
    } else {
        for (int k = t; k < nb; k += 256) {
            uint2 a = abuf[s0 + k];
            atomicAdd(&cnt[a.x >> 17], 1);
        }
    }
    __syncthreads();
    int v = (t < BNODES) ? cnt[t] : 0;
    scn[t] = v;
    __syncthreads();
    for (int off = 1; off < 256; off <<= 1) {
        int u = (t >= off) ? scn[t - off] : 0;
        __syncthreads();
        scn[t] += u;
        __syncthreads();
    }
    int excl = scn[t] - v;
    if (t < BNODES) {
        cur[t] = excl;
        int node = b * BNODES + t;
        if (node <= N_NODES) startA[node] = s0 + excl;
    }
    __syncthreads();
    if (fits) {
        for (int k = t; k < nb; k += 256) {
            uint2 a = se[k];
            int ln = (int)(a.x >> 17);
            int r  = (int)(a.x & 0x1FFFFu);
            float wn = __uint_as_float(a.y) * dinv[r];
            int off = atomicAdd(&cur[ln], 1);
            eperm[s0 + off] = make_uint2((unsigned)r, __float_as_uint(wn));
        }
    } else {
        for (int k = t; k < nb; k += 256) {
            uint2 a = abuf[s0 + k];
            int ln = (int)(a.x >> 17);
            int r  = (int)(a.x & 0x1FFFFu);
            float wn = __uint_as_float(a.y) * dinv[r];
            int off = atomicAdd(&cur[ln], 1);
            eperm[s0 + off] = make_uint2((unsigned)r, __float_as_uint(wn));
        }
    }
}

// ---------- layer 1 transform: h1 = x @ W1 ----------
// 128 rows/block x 782 blocks (3.05 blk/CU -> balanced; was 391 = 1.53/CU).
// Thread-per-row, 16 k-chunks of 32, x tile transposed in LDS (pad 129:
// write bank (4(t&7)+d + (t>>3) + 16p)%32 <=2-way = free; read (k+t)%32 free).
// W1 uniform -> s_load; register double-buffer hides HBM latency.

__global__ __launch_bounds__(128)
void k_gemm1(const float* __restrict__ x, const float* __restrict__ W1g,
             float* __restrict__ h1) {
    __shared__ float xT[32 * 129];          // 16.5 KB
    const int t = threadIdx.x;              // 0..127
    const int row0 = blockIdx.x * 128;
    const int myrow = row0 + t;

    float4 rg[8], rn[8];
#pragma unroll
    for (int p = 0; p < 8; ++p) {
        int f = t + 128 * p;                // 1024 float4 tile
        int lr = f >> 3, lc = f & 7;
        int gr = min(row0 + lr, N_NODES - 1);
        rg[p] = *(const float4*)(x + (size_t)gr * D_FEAT + 4 * lc);
    }

    float acc[16];
#pragma unroll
    for (int j = 0; j < 16; ++j) acc[j] = 0.0f;

    for (int ch = 0; ch < 16; ++ch) {
        __syncthreads();
#pragma unroll
        for (int p = 0; p < 8; ++p) {
            int f = t + 128 * p;
            int lr = f >> 3, lc = f & 7;
            xT[(4 * lc + 0) * 129 + lr] = rg[p].x;
            xT[(4 * lc + 1) * 129 + lr] = rg[p].y;
            xT[(4 * lc + 2) * 129 + lr] = rg[p].z;
            xT[(4 * lc + 3) * 129 + lr] = rg[p].w;
        }
        if (ch < 15) {
            int k0n = (ch + 1) * 32;
#pragma unroll
            for (int p = 0; p < 8; ++p) {
                int f = t + 128 * p;
                int lr = f >> 3, lc = f & 7;
                int gr = min(row0 + lr, N_NODES - 1);
                rn[p] = *(const float4*)(x + (size_t)gr * D_FEAT + k0n + 4 * lc);
            }
        }
        __syncthreads();
        const int k0 = ch * 32;
#pragma unroll
        for (int k = 0; k < 32; ++k) {
            float xk = xT[k * 129 + t];
            const float* wr = W1g + ((size_t)(k0 + k) << 4);
#pragma unroll
            for (int j = 0; j < 16; ++j) acc[j] = fmaf(xk, wr[j], acc[j]);
        }
#pragma unroll
        for (int p = 0; p < 8; ++p) rg[p] = rn[p];
    }

    if (myrow < N_NODES) {
        float4* o = (float4*)(h1 + (size_t)myrow * HIDDEN);
        o[0] = make_float4(acc[0],  acc[1],  acc[2],  acc[3]);
        o[1] = make_float4(acc[4],  acc[5],  acc[6],  acc[7]);
        o[2] = make_float4(acc[8],  acc[9],  acc[10], acc[11]);
        o[3] = make_float4(acc[12], acc[13], acc[14], acc[15]);
    }
}

// ---------- gather layer 1 (+ bias + self-loop) fused with gemm2 ----------
// 16 lanes/node = 4 edge-strides (es) x 4 float4-slices (fs); unroll-2 dual
// accumulators (8 independent chains/node). eperm.y holds w*dinv[row].

__global__ __launch_bounds__(256)
void k_gather1(const int* __restrict__ startA, const uint2* __restrict__ ep,
               const float* __restrict__ dinv, const float* __restrict__ h1,
               const float* __restrict__ b1, const float* __restrict__ W2g,
               float* __restrict__ x1, float* __restrict__ h2p) {
    __shared__ float sW2[HIDDEN * NCLS];
    __shared__ float sv[16][HIDDEN + 1];
    int t = threadIdx.x;
    if (t < HIDDEN * NCLS) sW2[t] = W2g[t];
    int ln = t >> 4, es = (t >> 2) & 3, fs = t & 3;
    int i = blockIdx.x * 16 + ln;
    bool act = (i < N_NODES);
    float4 a = make_float4(0.0f, 0.0f, 0.0f, 0.0f);
    float4 b = make_float4(0.0f, 0.0f, 0.0f, 0.0f);
    if (act) {
        int s0 = startA[i], n = startA[i + 1] - s0;
        int k = es;
        for (; k + 4 < n; k += 8) {
            uint2 e0 = ep[s0 + k];
            uint2 e1 = ep[s0 + k + 4];
            float w0 = __uint_as_float(e0.y);
            float w1 = __uint_as_float(e1.y);
            float4 h0 = *(const float4*)(h1 + ((size_t)e0.x << 4) + 4 * fs);
            float4 h4 = *(const float4*)(h1 + ((size_t)e1.x << 4) + 4 * fs);
            a.x = fmaf(w0, h0.x, a.x); a.y = fmaf(w0, h0.y, a.y);
            a.z = fmaf(w0, h0.z, a.z); a.w = fmaf(w0, h0.w, a.w);
            b.x = fmaf(w1, h4.x, b.x); b.y = fmaf(w1, h4.y, b.y);
            b.z = fmaf(w1, h4.z, b.z); b.w = fmaf(w1, h4.w, b.w);
        }
        if (k < n) {
            uint2 e0 = ep[s0 + k];
            float w0 = __uint_as_float(e0.y);
            float4 h0 = *(const float4*)(h1 + ((size_t)e0.x << 4) + 4 * fs);
            a.x = fmaf(w0, h0.x, a.x); a.y = fmaf(w0, h0.y, a.y);
            a.z = fmaf(w0, h0.z, a.z); a.w = fmaf(w0, h0.w, a.w);
        }
    }
    a.x += b.x; a.y += b.y; a.z += b.z; a.w += b.w;
    a.x += __shfl_xor(a.x, 4); a.y += __shfl_xor(a.y, 4);
    a.z += __shfl_xor(a.z, 4); a.w += __shfl_xor(a.w, 4);
    a.x += __shfl_xor(a.x, 8); a.y += __shfl_xor(a.y, 8);
    a.z += __shfl_xor(a.z, 8); a.w += __shfl_xor(a.w, 8);
    if (act && es == 0) {
        float di = dinv[i], d2 = di * di;
        const float* h1r = h1 + (size_t)i * HIDDEN + 4 * fs;
        const float* b1r = b1 + 4 * fs;
        float v0 = di * a.x + d2 * h1r[0] + b1r[0];
        float v1 = di * a.y + d2 * h1r[1] + b1r[1];
        float v2 = di * a.z + d2 * h1r[2] + b1r[2];
        float v3 = di * a.w + d2 * h1r[3] + b1r[3];
        *(float4*)(x1 + (size_t)i * HIDDEN + 4 * fs) = make_float4(v0, v1, v2, v3);
        sv[ln][4 * fs + 0] = v0; sv[ln][4 * fs + 1] = v1;
        sv[ln][4 * fs + 2] = v2; sv[ln][4 * fs + 3] = v3;
    }
    __syncthreads();
    int j = t & 15;
    if (act && j < 8) {
        float acc2 = 0.0f;
        if (j < NCLS) {
#pragma unroll
            for (int kk = 0; kk < HIDDEN; ++kk)
                acc2 = fmaf(sv[ln][kk], sW2[kk * NCLS + j], acc2);
        }
        h2p[(size_t)i * 8 + j] = acc2;             // cols 6,7 = 0 pad
    }
}

// ---------- gather layer 2 fused with log_softmax ----------
// 16 lanes/node = 8 edge-strides x 2 float4-slices on padded h2p[N,8];
// unroll-2 dual accumulators.

__global__ __launch_bounds__(256)
void k_gather2(const int* __restrict__ startA, const uint2* __restrict__ ep,
               const float* __restrict__ dinv, const float* __restrict__ h2p,
               const float* __restrict__ b2, float* __restrict__ out) {
    __shared__ float sv[16][9];
    int t = threadIdx.x;
    int ln = t >> 4, es = (t >> 1) & 7, fs = t & 1;
    int i = blockIdx.x * 16 + ln;
    bool act = (i < N_NODES);
    float4 a = make_float4(0.0f, 0.0f, 0.0f, 0.0f);
    float4 b = make_float4(0.0f, 0.0f, 0.0f, 0.0f);
    if (act) {
        int s0 = startA[i], n = startA[i + 1] - s0;
        int k = es;
        for (; k + 8 < n; k += 16) {
            uint2 e0 = ep[s0 + k];
            uint2 e1 = ep[s0 + k + 8];
            float w0 = __uint_as_float(e0.y);
            float w1 = __uint_as_float(e1.y);
            float4 h0 = *(const float4*)(h2p + ((size_t)e0.x << 3) + 4 * fs);
            float4 h8 = *(const float4*)(h2p + ((size_t)e1.x << 3) + 4 * fs);
            a.x = fmaf(w0, h0.x, a.x); a.y = fmaf(w0, h0.y, a.y);
            a.z = fmaf(w0, h0.z, a.z); a.w = fmaf(w0, h0.w, a.w);
            b.x = fmaf(w1, h8.x, b.x); b.y = fmaf(w1, h8.y, b.y);
            b.z = fmaf(w1, h8.z, b.z); b.w = fmaf(w1, h8.w, b.w);
        }
        if (k < n) {
            uint2 e0 = ep[s0 + k];
            float w0 = __uint_as_float(e0.y);
            float4 h0 = *(const float4*)(h2p + ((size_t)e0.x << 3) + 4 * fs);
            a.x = fmaf(w0, h0.x, a.x); a.y = fmaf(w0, h0.y, a.y);
            a.z = fmaf(w0, h0.z, a.z); a.w = fmaf(w0, h0.w, a.w);
        }
    }
    a.x += b.x; a.y += b.y; a.z += b.z; a.w += b.w;
    a.x += __shfl_xor(a.x, 2); a.y += __shfl_xor(a.y, 2);
    a.z += __shfl_xor(a.z, 2); a.w += __shfl_xor(a.w, 2);
    a.x += __shfl_xor(a.x, 4); a.y += __shfl_xor(a.y, 4);
    a.z += __shfl_xor(a.z, 4); a.w += __shfl_xor(a.w, 4);
    a.x += __shfl_xor(a.x, 8); a.y += __shfl_xor(a.y, 8);
    a.z += __shfl_xor(a.z, 8); a.w += __shfl_xor(a.w, 8);
    if (act && es == 0) {
        float di = dinv[i], d2 = di * di;
        const float* hr = h2p + (size_t)i * 8 + 4 * fs;
        int c0 = 4 * fs;
        float v0 = di * a.x + d2 * hr[0] + ((c0 + 0) < NCLS ? b2[c0 + 0] : 0.0f);
        float v1 = di * a.y + d2 * hr[1] + ((c0 + 1) < NCLS ? b2[c0 + 1] : 0.0f);
        float v2 = di * a.z + d2 * hr[2] + ((c0 + 2) < NCLS ? b2[c0 + 2] : 0.0f);
        float v3 = di * a.w + d2 * hr[3] + ((c0 + 3) < NCLS ? b2[c0 + 3] : 0.0f);
        sv[ln][c0 + 0] = v0; sv[ln][c0 + 1] = v1;
        sv[ln][c0 + 2] = v2; sv[ln][c0 + 3] = v3;
    }
    __syncthreads();
    int j = t & 15;
    if (act && j < NCLS) {
        float m = -1e30f;
#pragma unroll
        for (int c = 0; c < NCLS; ++c) m = fmaxf(m, sv[ln][c]);
        float ssum = 0.0f;
#pragma unroll
        for (int c = 0; c < NCLS; ++c) ssum += __expf(sv[ln][c] - m);
        out[(size_t)i * NCLS + j] = sv[ln][j] - m - __logf(ssum);
    }
}

// ---------- tier-3 atomic fallback kernels (small ws) ----------

__global__ void k_initdeg(float* __restrict__ deg) {
    int i = blockIdx.x * 256 + threadIdx.x;
    if (i < N_NODES) deg[i] = 1.0f;
}

__global__ void k_degacc(const int* __restrict__ ei, const float* __restrict__ w,
                         const int* __restrict__ flag, float* __restrict__ deg) {
    int e = blockIdx.x * 256 + threadIdx.x;
    if (e >= N_EDGES) return;
    int c = eidx(ei, flag[0], N_EDGES + e);
    atomicAdd(&deg[c], w[e]);
}

__global__ void k_dinv(float* __restrict__ deg) {
    int i = blockIdx.x * 256 + threadIdx.x;
    if (i < N_NODES) {
        float d = deg[i];
        deg[i] = (d > 0.0f) ? rsqrtf(d) : 0.0f;
    }
}

__global__ __launch_bounds__(256)
void k_scatter1(const int* __restrict__ ei, const float* __restrict__ w,
                const int* __restrict__ flag, const float* __restrict__ dinv,
                const float* __restrict__ h1, float* __restrict__ agg1) {
    int t = blockIdx.x * 256 + threadIdx.x;
    if (t >= N_EDGES * HIDDEN) return;
    int e = t >> 4, j = t & 15;
    int is64 = flag[0];
    int r = eidx(ei, is64, e);
    int c = eidx(ei, is64, N_EDGES + e);
    float nrm = dinv[r] * w[e] * dinv[c];
    atomicAdd(&agg1[(size_t)c * HIDDEN + j], nrm * h1[(size_t)r * HIDDEN + j]);
}

__global__ void k_fin1_gemm2(const float* __restrict__ b1, const float* __restrict__ W2,
                             const float* __restrict__ dinv, const float* __restrict__ h1,
                             float* __restrict__ x1, float* __restrict__ h2) {
    int i = blockIdx.x * 256 + threadIdx.x;
    if (i >= N_NODES) return;
    float d2 = dinv[i] * dinv[i];
    float v[HIDDEN];
#pragma unroll
    for (int k = 0; k < HIDDEN; ++k)
        v[k] = x1[(size_t)i * HIDDEN + k] + d2 * h1[(size_t)i * HIDDEN + k] + b1[k];
#pragma unroll
    for (int k = 0; k < HIDDEN; ++k)
        x1[(size_t)i * HIDDEN + k] = v[k];
#pragma unroll
    for (int j = 0; j < NCLS; ++j) {
        float a = 0.0f;
#pragma unroll
        for (int k = 0; k < HIDDEN; ++k) a = fmaf(v[k], W2[k * NCLS + j], a);
        h2[(size_t)i * NCLS + j] = a;
    }
}

__global__ __launch_bounds__(256)
void k_scatter2(const int* __restrict__ ei, const float* __restrict__ w,
                const int* __restrict__ flag, const float* __restrict__ dinv,
                const float* __restrict__ h2, float* __restrict__ agg2) {
    int t = blockIdx.x * 256 + threadIdx.x;
    if (t >= N_EDGES * NCLS) return;
    int e = t / NCLS, j = t - e * NCLS;
    int is64 = flag[0];
    int r = eidx(ei, is64, e);
    int c = eidx(ei, is64, N_EDGES + e);
    float nrm = dinv[r] * w[e] * dinv[c];
    atomicAdd(&agg2[(size_t)c * NCLS + j], nrm * h2[(size_t)r * NCLS + j]);
}

__global__ void k_final(const float* __restrict__ agg2, const float* __restrict__ h2,
                        const float* __restrict__ dinv, const float* __restrict__ b2,
                        float* __restrict__ out) {
    int i = blockIdx.x * 256 + threadIdx.x;
    if (i >= N_NODES) return;
    float d2 = dinv[i] * dinv[i];
    float v[NCLS];
    float m = -1e30f;
#pragma unroll
    for (int j = 0; j < NCLS; ++j) {
        v[j] = agg2[(size_t)i * NCLS + j] + d2 * h2[(size_t)i * NCLS + j] + b2[j];
        m = fmaxf(m, v[j]);
    }
    float s = 0.0f;
#pragma unroll
    for (int j = 0; j < NCLS; ++j) s += __expf(v[j] - m);
    float l = __logf(s);
#pragma unroll
    for (int j = 0; j < NCLS; ++j) out[(size_t)i * NCLS + j] = v[j] - m - l;
}

// ---------- launch ----------

extern "C" void kernel_launch(void* const* d_in, const int* in_sizes, int n_in,
                              void* d_out, int out_size, void* d_ws, size_t ws_size,
                              hipStream_t stream) {
    const float* x  = (const float*)d_in[0];
    const float* W1 = (const float*)d_in[1];
    const float* b1 = (const float*)d_in[2];
    const float* W2 = (const float*)d_in[3];
    const float* b2 = (const float*)d_in[4];
    const float* ew = (const float*)d_in[5];
    const int*   ei = (const int*)d_in[6];

    float* out = (float*)d_out;
    float* lsm = out;                               // [N, 6]
    float* x1  = out + (size_t)N_NODES * NCLS;      // [N, 16]

    const int NB_N = (N_NODES + 255) / 256;         // 391
    const int NB_E = (N_EDGES + 255) / 256;

    float* W    = (float*)d_ws;
    int*   flag = (int*)d_ws;

    // ---- tier-1 layout (4B words) ----
    int*   bcnt    = (int*)(W + 256);        // 783
    int*   bstart  = (int*)(W + 1152);       // 783
    int*   bcursor = (int*)(W + 2048);       // 782
    int*   startA  = (int*)(W + 2944);       // 100001 -> ends 102945
    float* dinvB   = W + 102948;             // 100000 -> ends 202948
    uint2* abuf    = (uint2*)(W + 202948);   // 3.2M uint2 -> ends 6602948; aliased:
    float* h1B     = W + 202948;             //   1.6M (written after abuf dies)
    float* h2p     = W + 1802948;            //   800K padded [N,8]
    uint2* eperm   = (uint2*)(W + 6602948);  // 3.2M uint2 -> ends 13002948
    const size_t NEED = (size_t)13002948 * 4;       // ~52.0 MB

    if (ws_size >= NEED) {
        hipMemsetAsync(bcnt, 0, (NBUK + 1) * 4, stream);
        k_detect<<<1, 64, 0, stream>>>(ei, flag);
        k_bhist <<<NBLK_A, 256, 0, stream>>>(ei, flag, bcnt);
        k_bscan <<<1, 1024, 0, stream>>>(bcnt, bstart, bcursor);
        k_bscat <<<NBLK_A, 256, 0, stream>>>(ei, ew, flag, bcursor, abuf);
        k_degB  <<<NBUK, 256, 0, stream>>>(bstart, abuf, dinvB);
        k_bsort <<<NBUK, 256, 0, stream>>>(bstart, abuf, dinvB, eperm, startA);
        k_gemm1 <<<(N_NODES + 127) / 128, 128, 0, stream>>>(x, W1, h1B);
        k_gather1<<<(N_NODES + 15) / 16, 256, 0, stream>>>(startA, eperm, dinvB, h1B,
                                                           b1, W2, x1, h2p);
        k_gather2<<<(N_NODES + 15) / 16, 256, 0, stream>>>(startA, eperm, dinvB, h2p,
                                                           b2, lsm);
    } else {
        float* deg  = W + 1024;
        float* fh1  = W + 101376;
        float* fh2  = fh1 + (size_t)N_NODES * HIDDEN;
        float* agg2 = fh2 + (size_t)N_NODES * NCLS;
        hipMemsetAsync(x1,   0, (size_t)N_NODES * HIDDEN * sizeof(float), stream);
        hipMemsetAsync(agg2, 0, (size_t)N_NODES * NCLS   * sizeof(float), stream);
        k_detect <<<1, 64, 0, stream>>>(ei, flag);
        k_initdeg<<<NB_N, 256, 0, stream>>>(deg);
        k_degacc <<<NB_E, 256, 0, stream>>>(ei, ew, flag, deg);
        k_dinv   <<<NB_N, 256, 0, stream>>>(deg);
        k_gemm1  <<<(N_NODES + 127) / 128, 128, 0, stream>>>(x, W1, fh1);
        k_scatter1<<<(N_EDGES * HIDDEN + 255) / 256, 256, 0, stream>>>(ei, ew, flag, deg, fh1, x1);
        k_fin1_gemm2<<<NB_N, 256, 0, stream>>>(b1, W2, deg, fh1, x1, fh2);
        k_scatter2<<<(N_EDGES * NCLS + 255) / 256, 256, 0, stream>>>(ei, ew, flag, deg, fh2, agg2);
        k_final  <<<NB_N, 256, 0, stream>>>(agg2, fh2, deg, b2, lsm);
    }
}